// Round 11
// baseline (19357.884 us; speedup 1.0000x reference)
//
#include <hip/hip_runtime.h>
#include <hip/hip_fp16.h>

#define B_SZ    64
#define T_STEPS 512
#define U1      128
#define S1      128
#define U2      256
#define S2      128
#define NUNF    6
#define RC2     6       // ltc2: LDS-resident chunks (of 16) per group; rest in VGPRs

typedef _Float16 h2f __attribute__((ext_vector_type(2)));

__device__ __forceinline__ float fast_exp2(float x) { return __builtin_amdgcn_exp2f(x); }
__device__ __forceinline__ float fast_rcp(float x)  { return __builtin_amdgcn_rcpf(x); }
__device__ __forceinline__ h2f u2h(unsigned u) { union { unsigned x; h2f h; } c; c.x = u; return c.h; }
__device__ __forceinline__ h2f pkrtz(float a, float b)
{
    return __builtin_bit_cast(h2f, __builtin_amdgcn_cvt_pkrtz(a, b));
}

// ---------------------------------------------------------------------------
// eval 4 synapse pairs: AB half2(A=sig*log2e, B=mu*sig*log2e), W half(w*erev).
// sigmoid((v-mu)*sig) = 1/(1+exp2(B-A*v)); |W| = w*mask (w>0).
// r packed to fp16 (pkrtz) and accumulated via v_dot2_f32_f16.
// ---------------------------------------------------------------------------
__device__ __forceinline__ void eval4d(uint4 ab4, uint2 w2, float4 vv,
                                       float& an, float& ad)
{
    h2f ab0 = u2h(ab4.x), ab1 = u2h(ab4.y), ab2 = u2h(ab4.z), ab3 = u2h(ab4.w);
    float r0 = fast_rcp(1.f + fast_exp2(fmaf(-(float)ab0[0], vv.x, (float)ab0[1])));
    float r1 = fast_rcp(1.f + fast_exp2(fmaf(-(float)ab1[0], vv.y, (float)ab1[1])));
    float r2 = fast_rcp(1.f + fast_exp2(fmaf(-(float)ab2[0], vv.z, (float)ab2[1])));
    float r3 = fast_rcp(1.f + fast_exp2(fmaf(-(float)ab3[0], vv.w, (float)ab3[1])));
    h2f rp01 = pkrtz(r0, r1);
    h2f rp23 = pkrtz(r2, r3);
    an = __builtin_amdgcn_fdot2(u2h(w2.x), rp01, an, false);
    an = __builtin_amdgcn_fdot2(u2h(w2.y), rp23, an, false);
    ad = __builtin_amdgcn_fdot2(u2h(w2.x & 0x7FFF7FFFu), rp01, ad, false);
    ad = __builtin_amdgcn_fdot2(u2h(w2.y & 0x7FFF7FFFu), rp23, ad, false);
}

// scalar variant (ltc1 / sens2k numerics, fma-based accumulation)
__device__ __forceinline__ void eval4(uint4 ab4, uint2 w2, float4 vv,
                                      float& an, float& ad)
{
    const unsigned abq[4] = {ab4.x, ab4.y, ab4.z, ab4.w};
    const float vals[4] = {vv.x, vv.y, vv.z, vv.w};
    #pragma unroll
    for (int q = 0; q < 4; ++q) {
        h2f ab = u2h(abq[q]);
        h2f wp = u2h((q < 2) ? w2.x : w2.y);
        float a  = (float)ab[0];
        float bb = (float)ab[1];
        float ww = (float)((q & 1) ? wp[1] : wp[0]);
        float e = fast_exp2(fmaf(-a, vals[q], bb));
        float r = fast_rcp(1.f + e);
        an = fmaf(ww, r, an);
        ad = fmaf(fabsf(ww), r, ad);
    }
}

// ---------------------------------------------------------------------------
// prep: chunked packing, linear layout [s4][u] (ltc1)
// ---------------------------------------------------------------------------
__global__ void prep_chunk(const float* __restrict__ sg, const float* __restrict__ mu,
                           const float* __restrict__ w, const float* __restrict__ er,
                           uint4* __restrict__ AB4, uint2* __restrict__ W2, int S4, int U)
{
    int i = blockIdx.x * 256 + threadIdx.x;
    if (i >= S4 * U) return;
    int uo = i % U, s4 = i / U;
    const float L2E = 1.4426950408889634f;
    unsigned ab[4]; __half wh[4];
    #pragma unroll
    for (int q = 0; q < 4; ++q) {
        size_t idx = (size_t)(s4 * 4 + q) * U + uo;
        float a = sg[idx] * L2E;
        __half2 h = __floats2half2_rn(a, mu[idx] * a);
        ab[q] = *reinterpret_cast<unsigned*>(&h);
        wh[q] = __float2half_rn(w[idx] * er[idx]);
    }
    __half2 w01 = __halves2half2(wh[0], wh[1]);
    __half2 w23 = __halves2half2(wh[2], wh[3]);
    AB4[i] = make_uint4(ab[0], ab[1], ab[2], ab[3]);
    W2[i]  = make_uint2(*reinterpret_cast<unsigned*>(&w01),
                        *reinterpret_cast<unsigned*>(&w23));
}

// prep: chunked packing, interleaved layout [c][u][g] for the butterfly kernel.
// s4 = g*CPG + c  ->  out index (c*U + u)*4 + g.
__global__ void prep_ilv(const float* __restrict__ sg, const float* __restrict__ mu,
                         const float* __restrict__ w, const float* __restrict__ er,
                         uint4* __restrict__ ABI, uint2* __restrict__ WI, int S4, int U, int CPG)
{
    int i = blockIdx.x * 256 + threadIdx.x;
    if (i >= S4 * U) return;
    int uo = i % U, s4 = i / U;
    int g = s4 / CPG, c = s4 % CPG;
    const float L2E = 1.4426950408889634f;
    unsigned ab[4]; __half wh[4];
    #pragma unroll
    for (int q = 0; q < 4; ++q) {
        size_t idx = (size_t)(s4 * 4 + q) * U + uo;
        float a = sg[idx] * L2E;
        __half2 h = __floats2half2_rn(a, mu[idx] * a);
        ab[q] = *reinterpret_cast<unsigned*>(&h);
        wh[q] = __float2half_rn(w[idx] * er[idx]);
    }
    __half2 w01 = __halves2half2(wh[0], wh[1]);
    __half2 w23 = __halves2half2(wh[2], wh[3]);
    int o = (c * U + uo) * 4 + g;
    ABI[o] = make_uint4(ab[0], ab[1], ab[2], ab[3]);
    WI[o]  = make_uint2(*reinterpret_cast<unsigned*>(&w01),
                        *reinterpret_cast<unsigned*>(&w23));
}

// linear fp16 pack (sens2k)
__global__ void prep_half(const float* __restrict__ sg, const float* __restrict__ mu,
                          const float* __restrict__ w, const float* __restrict__ er,
                          __half2* __restrict__ AB, __half* __restrict__ W, int n)
{
    int i = blockIdx.x * 256 + threadIdx.x;
    if (i >= n) return;
    const float L2E = 1.4426950408889634f;
    float a = sg[i] * L2E;
    AB[i] = __floats2half2_rn(a, mu[i] * a);
    W[i]  = __float2half_rn(w[i] * er[i]);
}

__global__ void prep_vec(const float* __restrict__ gleak, const float* __restrict__ vleak,
                         const float* __restrict__ cm,
                         float* __restrict__ cmt, float* __restrict__ nb,
                         float* __restrict__ db, int n)
{
    int i = blockIdx.x * 256 + threadIdx.x;
    if (i >= n) return;
    float c6 = cm[i] * 6.f;
    float gl = gleak[i];
    cmt[i] = c6;
    nb[i]  = gl * vleak[i];
    db[i]  = c6 + gl + 1e-8f;
}

// ---------------------------------------------------------------------------
// Layer 1: unchanged round-9 structure (~2.4 ms steady, not the bottleneck).
// ---------------------------------------------------------------------------
__global__ __launch_bounds__(1024, 1) void ltc1(
    const float* __restrict__ x,
    const float* __restrict__ in_w, const float* __restrict__ in_b,
    const uint4* __restrict__ AB4s, const uint2* __restrict__ W2s,
    const uint4* __restrict__ AB4r, const uint2* __restrict__ W2r,
    const float* __restrict__ cmt, const float* __restrict__ nbv, const float* __restrict__ dbv,
    const float* __restrict__ ow, const float* __restrict__ ob,
    float* __restrict__ h1)
{
    const int b   = blockIdx.x;
    const int tid = threadIdx.x;
    const int uo  = tid & (U1 - 1);
    const int g   = tid >> 7;

    __shared__ float  v1[U1], ibuf[S1], nbs[U1], dbs[U1];
    __shared__ float2 red[8][U1];
    __shared__ uint4  AB4l[32 * U1];
    __shared__ uint2  W2l[32 * U1];

    for (int idx = tid; idx < 32 * U1; idx += 1024) {
        AB4l[idx] = AB4r[idx];
        W2l[idx]  = W2r[idx];
    }

    float c_cmt = 0, c_nb = 0, c_db = 0, c_iw = 0, c_ib = 0, c_ow = 0, c_ob = 0;
    if (tid < U1) {
        v1[tid] = 0.f;
        c_cmt = cmt[tid]; c_nb = nbv[tid]; c_db = dbv[tid];
        c_iw = in_w[tid]; c_ib = in_b[tid];
        c_ow = ow[tid];   c_ob = ob[tid];
    }
    const float* xb = x  + (size_t)b * T_STEPS * S1;
    float*       hb = h1 + (size_t)b * T_STEPS * U1;
    __syncthreads();

    for (int t = 0; t < T_STEPS; ++t) {
        if (tid < S1) ibuf[tid] = fmaf(xb[t * S1 + tid], c_iw, c_ib);
        __syncthreads();

        {
            float an = 0.f, ad = 0.f;
            #pragma unroll 2
            for (int c = 0; c < 4; ++c) {
                uint4 ab = AB4s[(g * 4 + c) * U1 + uo];
                uint2 w2 = W2s[(g * 4 + c) * U1 + uo];
                float4 vv = *reinterpret_cast<const float4*>(&ibuf[g * 16 + c * 4]);
                eval4(ab, w2, vv, an, ad);
            }
            red[g][uo] = make_float2(an, ad);
        }
        __syncthreads();
        if (tid < U1) {
            float sn = c_nb, sd = c_db;
            #pragma unroll
            for (int gg = 0; gg < 8; ++gg) { float2 r = red[gg][tid]; sn += r.x; sd += r.y; }
            nbs[tid] = sn; dbs[tid] = sd;
        }
        __syncthreads();

        for (int k = 0; k < NUNF; ++k) {
            float an = 0.f, ad = 0.f;
            #pragma unroll
            for (int c = 0; c < 4; ++c) {
                uint4 ab = AB4l[(g * 4 + c) * U1 + uo];
                uint2 w2 = W2l[(g * 4 + c) * U1 + uo];
                float4 vv = *reinterpret_cast<const float4*>(&v1[g * 16 + c * 4]);
                eval4(ab, w2, vv, an, ad);
            }
            red[g][uo] = make_float2(an, ad);
            __syncthreads();
            if (tid < U1) {
                float sn = nbs[tid], sd = dbs[tid];
                #pragma unroll
                for (int gg = 0; gg < 8; ++gg) { float2 r = red[gg][tid]; sn += r.x; sd += r.y; }
                v1[tid] = fmaf(c_cmt, v1[tid], sn) * fast_rcp(sd);
            }
            __syncthreads();
        }
        if (tid < U1) hb[t * U1 + tid] = fmaf(v1[tid], c_ow, c_ob);
    }
}

// ---------------------------------------------------------------------------
// Layer-2 sensory sums, fully parallel over (b,t).
// ---------------------------------------------------------------------------
__global__ __launch_bounds__(256, 4) void sens2k(
    const float* __restrict__ h1,
    const float* __restrict__ in_w, const float* __restrict__ in_b,
    const __half2* __restrict__ ABs, const __half* __restrict__ Ws,
    float* __restrict__ sn, float* __restrict__ sd)
{
    const int tid = threadIdx.x;
    const int b   = blockIdx.x >> 7;
    const int t0  = (blockIdx.x & 127) << 2;

    __shared__ float ibu[4][S2];
    for (int idx = tid; idx < 4 * S2; idx += 256) {
        int tt = idx >> 7, s = idx & (S2 - 1);
        ibu[tt][s] = fmaf(h1[((size_t)b * T_STEPS + t0 + tt) * S2 + s], in_w[s], in_b[s]);
    }
    __syncthreads();

    const int u = tid;
    float an0 = 0, an1 = 0, an2 = 0, an3 = 0;
    float ad0 = 0, ad1 = 0, ad2 = 0, ad3 = 0;
    for (int s = 0; s < S2; ++s) {
        __half2 ab = ABs[(size_t)s * U2 + u];
        float a  = __low2float(ab);
        float bb = __high2float(ab);
        float ww = __half2float(Ws[(size_t)s * U2 + u]);
        float aw = fabsf(ww);
        float r0 = fast_rcp(1.f + fast_exp2(fmaf(-a, ibu[0][s], bb)));
        float r1 = fast_rcp(1.f + fast_exp2(fmaf(-a, ibu[1][s], bb)));
        float r2 = fast_rcp(1.f + fast_exp2(fmaf(-a, ibu[2][s], bb)));
        float r3 = fast_rcp(1.f + fast_exp2(fmaf(-a, ibu[3][s], bb)));
        an0 = fmaf(ww, r0, an0); ad0 = fmaf(aw, r0, ad0);
        an1 = fmaf(ww, r1, an1); ad1 = fmaf(aw, r1, ad1);
        an2 = fmaf(ww, r2, an2); ad2 = fmaf(aw, r2, ad2);
        an3 = fmaf(ww, r3, an3); ad3 = fmaf(aw, r3, ad3);
    }
    size_t base = ((size_t)b * T_STEPS + t0) * U2 + u;
    sn[base]          = an0; sd[base]          = ad0;
    sn[base + U2]     = an1; sd[base + U2]     = ad1;
    sn[base + 2 * U2] = an2; sd[base + 2 * U2] = ad2;
    sn[base + 3 * U2] = an3; sd[base + 3 * U2] = ad3;
}

// ---------------------------------------------------------------------------
// Layer 2, butterfly layout: 1024 thr = 16 waves.
// lane = ul*4+g: g = row-group (0..3, 64 rows), u = w*16+ul = column.
// Recurrent params: 6 chunks LDS-resident + 10 chunks REGISTER-resident
// (t-invariant, 60 VGPRs — fits the 128-VGPR cap at 16 waves/CU).
// Per unfold: eval 16 chunks -> 2x shfl_xor butterfly -> v update in-register
// -> publish to double-buffered 4-copy vbuf -> ONE barrier. Zero global reads.
// ---------------------------------------------------------------------------
template <bool HOIST>
__global__ __launch_bounds__(1024, 1) void ltc2(
    const float* __restrict__ h1,
    const float* __restrict__ in_w, const float* __restrict__ in_b,
    const uint4* __restrict__ ABsI, const uint2* __restrict__ WsI,
    const uint4* __restrict__ ABrI, const uint2* __restrict__ WrI,
    const float* __restrict__ sn, const float* __restrict__ sd,
    const float* __restrict__ cmt, const float* __restrict__ nbv, const float* __restrict__ dbv,
    const float* __restrict__ ow, const float* __restrict__ ob,
    float* __restrict__ h2)
{
    const int b    = blockIdx.x;
    const int tid  = threadIdx.x;
    const int w    = tid >> 6;
    const int lane = tid & 63;
    const int g    = lane & 3;
    const int ul   = lane >> 2;
    const int u    = w * 16 + ul;

    __shared__ uint4 ABl[RC2 * U2 * 4];     // 98304 B
    __shared__ uint2 Wl[RC2 * U2 * 4];      // 49152 B
    __shared__ float vbuf[2][4][68];        // dbuf x 4 bank-offset copies x 64 rows
    __shared__ float ibuf[S2];              // fallback sensory staging

    for (int idx = tid; idx < RC2 * U2 * 4; idx += 1024) {
        ABl[idx] = ABrI[idx];
        Wl[idx]  = WrI[idx];
    }
    for (int idx = tid; idx < 2 * 4 * 68; idx += 1024)
        (&vbuf[0][0][0])[idx] = 0.f;

    const uint4* pABr = ABrI + u * 4 + g;   // + c*1024 per chunk
    const uint2* pWr  = WrI  + u * 4 + g;
    const uint4* pABs = ABsI + u * 4 + g;
    const uint2* pWs  = WsI  + u * 4 + g;

    // register-cache the 10 non-LDS chunks (t- and k-invariant addresses)
    uint4 rAB[16 - RC2];
    uint2 rW[16 - RC2];
    #pragma unroll
    for (int c = 0; c < 16 - RC2; ++c) {
        rAB[c] = pABr[(size_t)(RC2 + c) * 1024];
        rW[c]  = pWr[(size_t)(RC2 + c) * 1024];
    }

    float v_reg = 0.f;
    const float c_cmt = cmt[u], c_nb = nbv[u], c_db = dbv[u];
    float c_ow = 0.f, c_ob = 0.f;
    if (u < 64) { c_ow = ow[u]; c_ob = ob[u]; }
    float c_iw = 0.f, c_ib = 0.f;
    if (!HOIST && tid < S2) { c_iw = in_w[tid]; c_ib = in_b[tid]; }

    const float* hb = h1 + (size_t)b * T_STEPS * S2;
    float*       op = h2 + (size_t)b * T_STEPS * 64;

    __syncthreads();
    int buf = 0;

    for (int t = 0; t < T_STEPS; ++t) {
        float nb_t, db_t;
        if (HOIST) {
            size_t ro = ((size_t)b * T_STEPS + t) * U2 + u;
            nb_t = c_nb + sn[ro];
            db_t = c_db + sd[ro];
        } else {
            if (tid < S2) ibuf[tid] = fmaf(hb[(size_t)t * S2 + tid], c_iw, c_ib);
            __syncthreads();
            float an = 0.f, ad = 0.f;
            #pragma unroll 2
            for (int c = 0; c < 8; ++c) {
                uint4 ab = pABs[c * 1024];
                uint2 w2 = pWs[c * 1024];
                float4 vv = *reinterpret_cast<const float4*>(&ibuf[g * 32 + c * 4]);
                eval4d(ab, w2, vv, an, ad);
            }
            an += __shfl_xor(an, 1, 64); ad += __shfl_xor(ad, 1, 64);
            an += __shfl_xor(an, 2, 64); ad += __shfl_xor(ad, 2, 64);
            nb_t = c_nb + an; db_t = c_db + ad;
        }

        #pragma unroll 1
        for (int k = 0; k < NUNF; ++k) {
            float an = 0.f, ad = 0.f;
            const float* vb = &vbuf[buf][g][0];
            // LDS-resident chunks (index = c*1024 + tid)
            #pragma unroll
            for (int c = 0; c < RC2; ++c) {
                uint4 ab = ABl[c * 1024 + tid];
                uint2 w2 = Wl[c * 1024 + tid];
                float4 vv = *reinterpret_cast<const float4*>(&vb[c * 4]);
                eval4d(ab, w2, vv, an, ad);
            }
            // register-resident chunks
            #pragma unroll
            for (int c = 0; c < 16 - RC2; ++c) {
                float4 vv = *reinterpret_cast<const float4*>(&vb[(RC2 + c) * 4]);
                eval4d(rAB[c], rW[c], vv, an, ad);
            }
            an += __shfl_xor(an, 1, 64); ad += __shfl_xor(ad, 1, 64);
            an += __shfl_xor(an, 2, 64); ad += __shfl_xor(ad, 2, 64);
            float wn = nb_t + an;
            float wd = db_t + ad;
            v_reg = fmaf(c_cmt, v_reg, wn) * fast_rcp(wd);
            if (g == 0) vbuf[buf ^ 1][w >> 2][(w & 3) * 16 + ul] = v_reg;
            buf ^= 1;
            __syncthreads();
        }
        if (u < 64 && g == 0) op[(size_t)t * 64 + u] = fmaf(v_reg, c_ow, c_ob);
    }
}

// ---------------------------------------------------------------------------
// FC head: out[b,t,o] = fcb[o] + sum_k h2[b,t,k] * fcw[o,k]
// ---------------------------------------------------------------------------
__global__ __launch_bounds__(512, 1) void fc_head(
    const float* __restrict__ h2, const float* __restrict__ fcw,
    const float* __restrict__ fcb, float* __restrict__ out)
{
    __shared__ float fwT[64 * 64];
    __shared__ float hs[8 * 64];
    const int tid = threadIdx.x;
    for (int i = tid; i < 64 * 64; i += 512) {
        int o = i >> 6, k = i & 63;
        fwT[k * 64 + o] = fcw[i];
    }
    size_t base = (size_t)blockIdx.x * 8 * 64;
    hs[tid] = h2[base + tid];
    __syncthreads();
    const int o = tid & 63, tt = tid >> 6;
    float acc = fcb[o];
    #pragma unroll
    for (int k = 0; k < 64; ++k)
        acc = fmaf(hs[tt * 64 + k], fwT[k * 64 + o], acc);
    out[base + tt * 64 + o] = acc;
}

// ---------------------------------------------------------------------------
extern "C" void kernel_launch(void* const* d_in, const int* in_sizes, int n_in,
                              void* d_out, int out_size, void* d_ws, size_t ws_size,
                              hipStream_t stream)
{
    (void)in_sizes; (void)n_in; (void)out_size;

    const float* x      = (const float*)d_in[0];
    const float* l1_iw  = (const float*)d_in[1];
    const float* l1_ib  = (const float*)d_in[2];
    const float* l1_sw  = (const float*)d_in[3];
    const float* l1_ss  = (const float*)d_in[4];
    const float* l1_smu = (const float*)d_in[5];
    const float* l1_se  = (const float*)d_in[6];
    const float* l1_w   = (const float*)d_in[8];
    const float* l1_sg  = (const float*)d_in[9];
    const float* l1_mu  = (const float*)d_in[10];
    const float* l1_er  = (const float*)d_in[11];
    const float* l1_gl  = (const float*)d_in[13];
    const float* l1_vl  = (const float*)d_in[14];
    const float* l1_cm  = (const float*)d_in[15];
    const float* l1_ow  = (const float*)d_in[16];
    const float* l1_ob  = (const float*)d_in[17];
    const float* l2_iw  = (const float*)d_in[18];
    const float* l2_ib  = (const float*)d_in[19];
    const float* l2_sw  = (const float*)d_in[20];
    const float* l2_ss  = (const float*)d_in[21];
    const float* l2_smu = (const float*)d_in[22];
    const float* l2_se  = (const float*)d_in[23];
    const float* l2_w   = (const float*)d_in[25];
    const float* l2_sg  = (const float*)d_in[26];
    const float* l2_mu  = (const float*)d_in[27];
    const float* l2_er  = (const float*)d_in[28];
    const float* l2_gl  = (const float*)d_in[30];
    const float* l2_vl  = (const float*)d_in[31];
    const float* l2_cm  = (const float*)d_in[32];
    const float* l2_ow  = (const float*)d_in[33];
    const float* l2_ob  = (const float*)d_in[34];
    const float* fcw    = (const float*)d_in[35];
    const float* fcb    = (const float*)d_in[36];

    char*  base = (char*)d_ws;
    size_t off  = 0;
    auto alloc = [&](size_t bytes) -> char* {
        char* p = base + off;
        off += (bytes + 255) & ~(size_t)255;
        return p;
    };

    float* h1 = (float*)alloc((size_t)B_SZ * T_STEPS * U1 * 4);
    float* h2 = (float*)alloc((size_t)B_SZ * T_STEPS * 64 * 4);
    // ltc1 linear-chunked params
    uint4* AB4s1 = (uint4*)alloc((size_t)(S1 / 4) * U1 * 16);
    uint2* W2s1  = (uint2*)alloc((size_t)(S1 / 4) * U1 * 8);
    uint4* AB4r1 = (uint4*)alloc((size_t)(U1 / 4) * U1 * 16);
    uint2* W2r1  = (uint2*)alloc((size_t)(U1 / 4) * U1 * 8);
    // ltc2 interleaved params
    uint4* ABsI2 = (uint4*)alloc((size_t)(S2 / 4) * U2 * 16);
    uint2* WsI2  = (uint2*)alloc((size_t)(S2 / 4) * U2 * 8);
    uint4* ABrI2 = (uint4*)alloc((size_t)(U2 / 4) * U2 * 16);
    uint2* WrI2  = (uint2*)alloc((size_t)(U2 / 4) * U2 * 8);
    // linear fp16 (sens2k)
    __half2* AB2s = (__half2*)alloc((size_t)S2 * U2 * 4);
    __half*  W2s  = (__half*) alloc((size_t)S2 * U2 * 2);
    float* cmt1 = (float*)alloc(U1 * 4);
    float* nb1  = (float*)alloc(U1 * 4);
    float* db1  = (float*)alloc(U1 * 4);
    float* cmt2 = (float*)alloc(U2 * 4);
    float* nb2  = (float*)alloc(U2 * 4);
    float* db2  = (float*)alloc(U2 * 4);

    size_t sens_bytes = (size_t)B_SZ * T_STEPS * U2 * 4;
    bool hoist = (off + 2 * sens_bytes + 512) <= ws_size;
    float* sn2 = nullptr; float* sd2 = nullptr;
    if (hoist) {
        sn2 = (float*)alloc(sens_bytes);
        sd2 = (float*)alloc(sens_bytes);
    }

    prep_chunk<<<((S1/4)*U1 + 255)/256, 256, 0, stream>>>(l1_ss, l1_smu, l1_sw, l1_se, AB4s1, W2s1, S1/4, U1);
    prep_chunk<<<((U1/4)*U1 + 255)/256, 256, 0, stream>>>(l1_sg, l1_mu,  l1_w,  l1_er, AB4r1, W2r1, U1/4, U1);
    prep_ilv<<<((S2/4)*U2 + 255)/256, 256, 0, stream>>>(l2_ss, l2_smu, l2_sw, l2_se, ABsI2, WsI2, S2/4, U2, 8);
    prep_ilv<<<((U2/4)*U2 + 255)/256, 256, 0, stream>>>(l2_sg, l2_mu,  l2_w,  l2_er, ABrI2, WrI2, U2/4, U2, 16);
    prep_half<<<(S2 * U2 + 255)/256, 256, 0, stream>>>(l2_ss, l2_smu, l2_sw, l2_se, AB2s, W2s, S2 * U2);
    prep_vec<<<1, 256, 0, stream>>>(l1_gl, l1_vl, l1_cm, cmt1, nb1, db1, U1);
    prep_vec<<<1, 256, 0, stream>>>(l2_gl, l2_vl, l2_cm, cmt2, nb2, db2, U2);

    ltc1<<<B_SZ, 1024, 0, stream>>>(x, l1_iw, l1_ib, AB4s1, W2s1, AB4r1, W2r1,
                                    cmt1, nb1, db1, l1_ow, l1_ob, h1);

    if (hoist) {
        sens2k<<<B_SZ * (T_STEPS / 4), 256, 0, stream>>>(h1, l2_iw, l2_ib, AB2s, W2s, sn2, sd2);
        ltc2<true><<<B_SZ, 1024, 0, stream>>>(h1, l2_iw, l2_ib, ABsI2, WsI2, ABrI2, WrI2,
                                              sn2, sd2, cmt2, nb2, db2, l2_ow, l2_ob, h2);
    } else {
        ltc2<false><<<B_SZ, 1024, 0, stream>>>(h1, l2_iw, l2_ib, ABsI2, WsI2, ABrI2, WrI2,
                                               nullptr, nullptr, cmt2, nb2, db2, l2_ow, l2_ob, h2);
    }
    fc_head<<<B_SZ * T_STEPS / 8, 512, 0, stream>>>(h2, fcw, fcb, (float*)d_out);
}

// Round 12
// 18655.933 us; speedup vs baseline: 1.0376x; 1.0376x over previous
//
#include <hip/hip_runtime.h>
#include <hip/hip_fp16.h>

#define B_SZ    64
#define T_STEPS 512
#define U1      128
#define S1      128
#define U2      256
#define S2      128
#define NUNF    6
#define RC2     6       // ltc2: LDS-resident chunks (of 16) per group

typedef _Float16 h2f __attribute__((ext_vector_type(2)));

__device__ __forceinline__ float fast_exp2(float x) { return __builtin_amdgcn_exp2f(x); }
__device__ __forceinline__ float fast_rcp(float x)  { return __builtin_amdgcn_rcpf(x); }
__device__ __forceinline__ h2f u2h(unsigned u) { union { unsigned x; h2f h; } c; c.x = u; return c.h; }
__device__ __forceinline__ h2f pkrtz(float a, float b)
{
    return __builtin_bit_cast(h2f, __builtin_amdgcn_cvt_pkrtz(a, b));
}

// ---------------------------------------------------------------------------
// eval 4 synapse pairs: AB half2(A=sig*log2e, B=mu*sig*log2e), W half(w*erev).
// sigmoid((v-mu)*sig) = 1/(1+exp2(B-A*v)); |W| = w*mask (w>0).
// ---------------------------------------------------------------------------
__device__ __forceinline__ void eval4d(uint4 ab4, uint2 w2, float4 vv,
                                       float& an, float& ad)
{
    h2f ab0 = u2h(ab4.x), ab1 = u2h(ab4.y), ab2 = u2h(ab4.z), ab3 = u2h(ab4.w);
    float r0 = fast_rcp(1.f + fast_exp2(fmaf(-(float)ab0[0], vv.x, (float)ab0[1])));
    float r1 = fast_rcp(1.f + fast_exp2(fmaf(-(float)ab1[0], vv.y, (float)ab1[1])));
    float r2 = fast_rcp(1.f + fast_exp2(fmaf(-(float)ab2[0], vv.z, (float)ab2[1])));
    float r3 = fast_rcp(1.f + fast_exp2(fmaf(-(float)ab3[0], vv.w, (float)ab3[1])));
    h2f rp01 = pkrtz(r0, r1);
    h2f rp23 = pkrtz(r2, r3);
    an = __builtin_amdgcn_fdot2(u2h(w2.x), rp01, an, false);
    an = __builtin_amdgcn_fdot2(u2h(w2.y), rp23, an, false);
    ad = __builtin_amdgcn_fdot2(u2h(w2.x & 0x7FFF7FFFu), rp01, ad, false);
    ad = __builtin_amdgcn_fdot2(u2h(w2.y & 0x7FFF7FFFu), rp23, ad, false);
}

// ---------------------------------------------------------------------------
// prep: chunked packing, interleaved layout [c][u][g]: s4 = g*CPG + c,
// out index (c*U + uo)*NG + g.  Lane (u,g) then reads entry c*U*NG + tid.
// ---------------------------------------------------------------------------
__global__ void prep_ilv(const float* __restrict__ sg, const float* __restrict__ mu,
                         const float* __restrict__ w, const float* __restrict__ er,
                         uint4* __restrict__ ABI, uint2* __restrict__ WI,
                         int S4, int U, int CPG, int NG)
{
    int i = blockIdx.x * 256 + threadIdx.x;
    if (i >= S4 * U) return;
    int uo = i % U, s4 = i / U;
    int g = s4 / CPG, c = s4 % CPG;
    const float L2E = 1.4426950408889634f;
    unsigned ab[4]; __half wh[4];
    #pragma unroll
    for (int q = 0; q < 4; ++q) {
        size_t idx = (size_t)(s4 * 4 + q) * U + uo;
        float a = sg[idx] * L2E;
        __half2 h = __floats2half2_rn(a, mu[idx] * a);
        ab[q] = *reinterpret_cast<unsigned*>(&h);
        wh[q] = __float2half_rn(w[idx] * er[idx]);
    }
    __half2 w01 = __halves2half2(wh[0], wh[1]);
    __half2 w23 = __halves2half2(wh[2], wh[3]);
    int o = (c * U + uo) * NG + g;
    ABI[o] = make_uint4(ab[0], ab[1], ab[2], ab[3]);
    WI[o]  = make_uint2(*reinterpret_cast<unsigned*>(&w01),
                        *reinterpret_cast<unsigned*>(&w23));
}

// linear fp16 pack (sens1k / sens2k)
__global__ void prep_half(const float* __restrict__ sg, const float* __restrict__ mu,
                          const float* __restrict__ w, const float* __restrict__ er,
                          __half2* __restrict__ AB, __half* __restrict__ W, int n)
{
    int i = blockIdx.x * 256 + threadIdx.x;
    if (i >= n) return;
    const float L2E = 1.4426950408889634f;
    float a = sg[i] * L2E;
    AB[i] = __floats2half2_rn(a, mu[i] * a);
    W[i]  = __float2half_rn(w[i] * er[i]);
}

__global__ void prep_vec(const float* __restrict__ gleak, const float* __restrict__ vleak,
                         const float* __restrict__ cm,
                         float* __restrict__ cmt, float* __restrict__ nb,
                         float* __restrict__ db, int n)
{
    int i = blockIdx.x * 256 + threadIdx.x;
    if (i >= n) return;
    float c6 = cm[i] * 6.f;
    float gl = gleak[i];
    cmt[i] = c6;
    nb[i]  = gl * vleak[i];
    db[i]  = c6 + gl + 1e-8f;
}

// ---------------------------------------------------------------------------
// Layer-1 sensory sums, fully parallel over (b,t): all 256 CUs.
// 256 threads = 2 halves x 128 units; 8 timesteps per block.
// ---------------------------------------------------------------------------
__global__ __launch_bounds__(256, 4) void sens1k(
    const float* __restrict__ x,
    const float* __restrict__ in_w, const float* __restrict__ in_b,
    const __half2* __restrict__ ABs, const __half* __restrict__ Ws,
    float* __restrict__ sn, float* __restrict__ sd)
{
    const int tid = threadIdx.x;
    const int b   = blockIdx.x >> 6;          // T/8 = 64 blocks per batch
    const int t0  = (blockIdx.x & 63) << 3;
    const int u   = tid & 127;
    const int hf  = tid >> 7;                 // 0,1

    __shared__ float ibu[8][S1];
    for (int idx = tid; idx < 8 * S1; idx += 256) {
        int tt = idx >> 7, s = idx & (S1 - 1);
        ibu[tt][s] = fmaf(x[((size_t)b * T_STEPS + t0 + tt) * S1 + s], in_w[s], in_b[s]);
    }
    __syncthreads();

    float an0 = 0, an1 = 0, an2 = 0, an3 = 0;
    float ad0 = 0, ad1 = 0, ad2 = 0, ad3 = 0;
    const int tb = hf * 4;
    for (int s = 0; s < S1; ++s) {
        __half2 ab = ABs[(size_t)s * U1 + u];
        float a  = __low2float(ab);
        float bb = __high2float(ab);
        float ww = __half2float(Ws[(size_t)s * U1 + u]);
        float aw = fabsf(ww);
        float r0 = fast_rcp(1.f + fast_exp2(fmaf(-a, ibu[tb + 0][s], bb)));
        float r1 = fast_rcp(1.f + fast_exp2(fmaf(-a, ibu[tb + 1][s], bb)));
        float r2 = fast_rcp(1.f + fast_exp2(fmaf(-a, ibu[tb + 2][s], bb)));
        float r3 = fast_rcp(1.f + fast_exp2(fmaf(-a, ibu[tb + 3][s], bb)));
        an0 = fmaf(ww, r0, an0); ad0 = fmaf(aw, r0, ad0);
        an1 = fmaf(ww, r1, an1); ad1 = fmaf(aw, r1, ad1);
        an2 = fmaf(ww, r2, an2); ad2 = fmaf(aw, r2, ad2);
        an3 = fmaf(ww, r3, an3); ad3 = fmaf(aw, r3, ad3);
    }
    size_t base = ((size_t)b * T_STEPS + t0 + tb) * U1 + u;
    sn[base]          = an0; sd[base]          = ad0;
    sn[base + U1]     = an1; sd[base + U1]     = ad1;
    sn[base + 2 * U1] = an2; sd[base + 2 * U1] = ad2;
    sn[base + 3 * U1] = an3; sd[base + 3 * U1] = ad3;
}

// ---------------------------------------------------------------------------
// Layer 1, butterfly: 1024 thr = 16 waves. lane = ul*8+g: g = row-group
// (0..7, 16 rows each), u = w*8+ul = column (128).  ALL recurrent params
// LDS-resident (96 KB).  Per unfold: eval 4 chunks -> 3x shfl_xor -> v update
// -> publish to dbuf vbuf -> ONE barrier.  Sensory hoisted (HOIST1) or inline.
// ---------------------------------------------------------------------------
template <bool HOIST1>
__global__ __launch_bounds__(1024, 1) void ltc1(
    const float* __restrict__ x,
    const float* __restrict__ in_w, const float* __restrict__ in_b,
    const uint4* __restrict__ ABsI, const uint2* __restrict__ WsI,
    const uint4* __restrict__ ABrI, const uint2* __restrict__ WrI,
    const float* __restrict__ sn, const float* __restrict__ sd,
    const float* __restrict__ cmt, const float* __restrict__ nbv, const float* __restrict__ dbv,
    const float* __restrict__ ow, const float* __restrict__ ob,
    float* __restrict__ h1)
{
    const int b    = blockIdx.x;
    const int tid  = threadIdx.x;
    const int w    = tid >> 6;
    const int lane = tid & 63;
    const int g    = lane & 7;               // 8 groups x 16 rows
    const int ul   = lane >> 3;
    const int u    = w * 8 + ul;              // 128 columns

    __shared__ uint4 ABl[4 * 1024];           // 64 KB
    __shared__ uint2 Wl[4 * 1024];            // 32 KB
    __shared__ float vbuf[2][8][20];          // group-partitioned rows, dbuf
    __shared__ float ibuf[S1];                // inline-sensory staging

    for (int idx = tid; idx < 4 * 1024; idx += 1024) {
        ABl[idx] = ABrI[idx];
        Wl[idx]  = WsI == nullptr ? Wl[idx] : WrI[idx];
    }
    for (int idx = tid; idx < 2 * 8 * 20; idx += 1024)
        (&vbuf[0][0][0])[idx] = 0.f;

    float v_reg = 0.f;
    const float c_cmt = cmt[u], c_nb = nbv[u], c_db = dbv[u];
    const float c_ow = ow[u], c_ob = ob[u];
    float c_iw = 0.f, c_ib = 0.f;
    if (!HOIST1 && tid < S1) { c_iw = in_w[tid]; c_ib = in_b[tid]; }

    const float* xb = x  + (size_t)b * T_STEPS * S1;
    float*       hb = h1 + (size_t)b * T_STEPS * U1;
    const uint4* pABs = ABsI + tid;           // + c*1024 per chunk
    const uint2* pWs  = WsI  + tid;

    __syncthreads();
    int buf = 0;

    for (int t = 0; t < T_STEPS; ++t) {
        float nb_t, db_t;
        if (HOIST1) {
            size_t ro = ((size_t)b * T_STEPS + t) * U1 + u;
            nb_t = c_nb + sn[ro];
            db_t = c_db + sd[ro];
        } else {
            if (tid < S1) ibuf[tid] = fmaf(xb[(size_t)t * S1 + tid], c_iw, c_ib);
            __syncthreads();
            float an = 0.f, ad = 0.f;
            #pragma unroll
            for (int c = 0; c < 4; ++c) {
                uint4 ab = pABs[c * 1024];
                uint2 w2 = pWs[c * 1024];
                float4 vv = *reinterpret_cast<const float4*>(&ibuf[g * 16 + c * 4]);
                eval4d(ab, w2, vv, an, ad);
            }
            an += __shfl_xor(an, 1, 64); ad += __shfl_xor(ad, 1, 64);
            an += __shfl_xor(an, 2, 64); ad += __shfl_xor(ad, 2, 64);
            an += __shfl_xor(an, 4, 64); ad += __shfl_xor(ad, 4, 64);
            nb_t = c_nb + an; db_t = c_db + ad;
        }

        #pragma unroll 1
        for (int k = 0; k < NUNF; ++k) {
            float an = 0.f, ad = 0.f;
            const float* vb = &vbuf[buf][g][0];
            #pragma unroll
            for (int c = 0; c < 4; ++c) {
                uint4 ab = ABl[c * 1024 + tid];
                uint2 w2 = Wl[c * 1024 + tid];
                float4 vv = *reinterpret_cast<const float4*>(&vb[c * 4]);
                eval4d(ab, w2, vv, an, ad);
            }
            an += __shfl_xor(an, 1, 64); ad += __shfl_xor(ad, 1, 64);
            an += __shfl_xor(an, 2, 64); ad += __shfl_xor(ad, 2, 64);
            an += __shfl_xor(an, 4, 64); ad += __shfl_xor(ad, 4, 64);
            float wn = nb_t + an;
            float wd = db_t + ad;
            v_reg = fmaf(c_cmt, v_reg, wn) * fast_rcp(wd);
            if (g == 0) vbuf[buf ^ 1][w >> 1][(w & 1) * 8 + ul] = v_reg;
            buf ^= 1;
            __syncthreads();
        }
        if (g == 0) hb[(size_t)t * U1 + u] = fmaf(v_reg, c_ow, c_ob);
    }
}

// ---------------------------------------------------------------------------
// Layer-2 sensory sums, fully parallel over (b,t).
// ---------------------------------------------------------------------------
__global__ __launch_bounds__(256, 4) void sens2k(
    const float* __restrict__ h1,
    const float* __restrict__ in_w, const float* __restrict__ in_b,
    const __half2* __restrict__ ABs, const __half* __restrict__ Ws,
    float* __restrict__ sn, float* __restrict__ sd)
{
    const int tid = threadIdx.x;
    const int b   = blockIdx.x >> 7;
    const int t0  = (blockIdx.x & 127) << 2;

    __shared__ float ibu[4][S2];
    for (int idx = tid; idx < 4 * S2; idx += 256) {
        int tt = idx >> 7, s = idx & (S2 - 1);
        ibu[tt][s] = fmaf(h1[((size_t)b * T_STEPS + t0 + tt) * S2 + s], in_w[s], in_b[s]);
    }
    __syncthreads();

    const int u = tid;
    float an0 = 0, an1 = 0, an2 = 0, an3 = 0;
    float ad0 = 0, ad1 = 0, ad2 = 0, ad3 = 0;
    for (int s = 0; s < S2; ++s) {
        __half2 ab = ABs[(size_t)s * U2 + u];
        float a  = __low2float(ab);
        float bb = __high2float(ab);
        float ww = __half2float(Ws[(size_t)s * U2 + u]);
        float aw = fabsf(ww);
        float r0 = fast_rcp(1.f + fast_exp2(fmaf(-a, ibu[0][s], bb)));
        float r1 = fast_rcp(1.f + fast_exp2(fmaf(-a, ibu[1][s], bb)));
        float r2 = fast_rcp(1.f + fast_exp2(fmaf(-a, ibu[2][s], bb)));
        float r3 = fast_rcp(1.f + fast_exp2(fmaf(-a, ibu[3][s], bb)));
        an0 = fmaf(ww, r0, an0); ad0 = fmaf(aw, r0, ad0);
        an1 = fmaf(ww, r1, an1); ad1 = fmaf(aw, r1, ad1);
        an2 = fmaf(ww, r2, an2); ad2 = fmaf(aw, r2, ad2);
        an3 = fmaf(ww, r3, an3); ad3 = fmaf(aw, r3, ad3);
    }
    size_t base = ((size_t)b * T_STEPS + t0) * U2 + u;
    sn[base]          = an0; sd[base]          = ad0;
    sn[base + U2]     = an1; sd[base + U2]     = ad1;
    sn[base + 2 * U2] = an2; sd[base + 2 * U2] = ad2;
    sn[base + 3 * U2] = an3; sd[base + 3 * U2] = ad3;
}

// ---------------------------------------------------------------------------
// Layer 2, butterfly (round-11 structure + dual accumulation chains).
// ---------------------------------------------------------------------------
template <bool HOIST>
__global__ __launch_bounds__(1024, 1) void ltc2(
    const float* __restrict__ h1,
    const float* __restrict__ in_w, const float* __restrict__ in_b,
    const uint4* __restrict__ ABsI, const uint2* __restrict__ WsI,
    const uint4* __restrict__ ABrI, const uint2* __restrict__ WrI,
    const float* __restrict__ sn, const float* __restrict__ sd,
    const float* __restrict__ cmt, const float* __restrict__ nbv, const float* __restrict__ dbv,
    const float* __restrict__ ow, const float* __restrict__ ob,
    float* __restrict__ h2)
{
    const int b    = blockIdx.x;
    const int tid  = threadIdx.x;
    const int w    = tid >> 6;
    const int lane = tid & 63;
    const int g    = lane & 3;
    const int ul   = lane >> 2;
    const int u    = w * 16 + ul;

    __shared__ uint4 ABl[RC2 * U2 * 4];
    __shared__ uint2 Wl[RC2 * U2 * 4];
    __shared__ float vbuf[2][4][68];
    __shared__ float ibuf[S2];

    for (int idx = tid; idx < RC2 * U2 * 4; idx += 1024) {
        ABl[idx] = ABrI[idx];
        Wl[idx]  = WrI[idx];
    }
    for (int idx = tid; idx < 2 * 4 * 68; idx += 1024)
        (&vbuf[0][0][0])[idx] = 0.f;

    const uint4* pABr = ABrI + u * 4 + g;
    const uint2* pWr  = WrI  + u * 4 + g;
    const uint4* pABs = ABsI + u * 4 + g;
    const uint2* pWs  = WsI  + u * 4 + g;

    float v_reg = 0.f;
    const float c_cmt = cmt[u], c_nb = nbv[u], c_db = dbv[u];
    float c_ow = 0.f, c_ob = 0.f;
    if (u < 64) { c_ow = ow[u]; c_ob = ob[u]; }
    float c_iw = 0.f, c_ib = 0.f;
    if (!HOIST && tid < S2) { c_iw = in_w[tid]; c_ib = in_b[tid]; }

    const float* hb = h1 + (size_t)b * T_STEPS * S2;
    float*       op = h2 + (size_t)b * T_STEPS * 64;

    __syncthreads();
    int buf = 0;

    for (int t = 0; t < T_STEPS; ++t) {
        float nb_t, db_t;
        if (HOIST) {
            size_t ro = ((size_t)b * T_STEPS + t) * U2 + u;
            nb_t = c_nb + sn[ro];
            db_t = c_db + sd[ro];
        } else {
            if (tid < S2) ibuf[tid] = fmaf(hb[(size_t)t * S2 + tid], c_iw, c_ib);
            __syncthreads();
            float an = 0.f, ad = 0.f;
            #pragma unroll 2
            for (int c = 0; c < 8; ++c) {
                uint4 ab = pABs[c * 1024];
                uint2 w2 = pWs[c * 1024];
                float4 vv = *reinterpret_cast<const float4*>(&ibuf[g * 32 + c * 4]);
                eval4d(ab, w2, vv, an, ad);
            }
            an += __shfl_xor(an, 1, 64); ad += __shfl_xor(ad, 1, 64);
            an += __shfl_xor(an, 2, 64); ad += __shfl_xor(ad, 2, 64);
            nb_t = c_nb + an; db_t = c_db + ad;
        }

        #pragma unroll 1
        for (int k = 0; k < NUNF; ++k) {
            float anL = 0.f, adL = 0.f, anR = 0.f, adR = 0.f;
            const float* vb = &vbuf[buf][g][0];
            #pragma unroll
            for (int c = 0; c < RC2; ++c) {
                uint4 ab = ABl[c * 1024 + tid];
                uint2 w2 = Wl[c * 1024 + tid];
                float4 vv = *reinterpret_cast<const float4*>(&vb[c * 4]);
                eval4d(ab, w2, vv, anL, adL);
            }
            #pragma unroll 2
            for (int c = RC2; c < 16; ++c) {
                uint4 ab = pABr[c * 1024];
                uint2 w2 = pWr[c * 1024];
                float4 vv = *reinterpret_cast<const float4*>(&vb[c * 4]);
                eval4d(ab, w2, vv, anR, adR);
            }
            float an = anL + anR, ad = adL + adR;
            an += __shfl_xor(an, 1, 64); ad += __shfl_xor(ad, 1, 64);
            an += __shfl_xor(an, 2, 64); ad += __shfl_xor(ad, 2, 64);
            float wn = nb_t + an;
            float wd = db_t + ad;
            v_reg = fmaf(c_cmt, v_reg, wn) * fast_rcp(wd);
            if (g == 0) vbuf[buf ^ 1][w >> 2][(w & 3) * 16 + ul] = v_reg;
            buf ^= 1;
            __syncthreads();
        }
        if (u < 64 && g == 0) op[(size_t)t * 64 + u] = fmaf(v_reg, c_ow, c_ob);
    }
}

// ---------------------------------------------------------------------------
// FC head: out[b,t,o] = fcb[o] + sum_k h2[b,t,k] * fcw[o,k]
// ---------------------------------------------------------------------------
__global__ __launch_bounds__(512, 1) void fc_head(
    const float* __restrict__ h2, const float* __restrict__ fcw,
    const float* __restrict__ fcb, float* __restrict__ out)
{
    __shared__ float fwT[64 * 64];
    __shared__ float hs[8 * 64];
    const int tid = threadIdx.x;
    for (int i = tid; i < 64 * 64; i += 512) {
        int o = i >> 6, k = i & 63;
        fwT[k * 64 + o] = fcw[i];
    }
    size_t base = (size_t)blockIdx.x * 8 * 64;
    hs[tid] = h2[base + tid];
    __syncthreads();
    const int o = tid & 63, tt = tid >> 6;
    float acc = fcb[o];
    #pragma unroll
    for (int k = 0; k < 64; ++k)
        acc = fmaf(hs[tt * 64 + k], fwT[k * 64 + o], acc);
    out[base + tt * 64 + o] = acc;
}

// ---------------------------------------------------------------------------
extern "C" void kernel_launch(void* const* d_in, const int* in_sizes, int n_in,
                              void* d_out, int out_size, void* d_ws, size_t ws_size,
                              hipStream_t stream)
{
    (void)in_sizes; (void)n_in; (void)out_size;

    const float* x      = (const float*)d_in[0];
    const float* l1_iw  = (const float*)d_in[1];
    const float* l1_ib  = (const float*)d_in[2];
    const float* l1_sw  = (const float*)d_in[3];
    const float* l1_ss  = (const float*)d_in[4];
    const float* l1_smu = (const float*)d_in[5];
    const float* l1_se  = (const float*)d_in[6];
    const float* l1_w   = (const float*)d_in[8];
    const float* l1_sg  = (const float*)d_in[9];
    const float* l1_mu  = (const float*)d_in[10];
    const float* l1_er  = (const float*)d_in[11];
    const float* l1_gl  = (const float*)d_in[13];
    const float* l1_vl  = (const float*)d_in[14];
    const float* l1_cm  = (const float*)d_in[15];
    const float* l1_ow  = (const float*)d_in[16];
    const float* l1_ob  = (const float*)d_in[17];
    const float* l2_iw  = (const float*)d_in[18];
    const float* l2_ib  = (const float*)d_in[19];
    const float* l2_sw  = (const float*)d_in[20];
    const float* l2_ss  = (const float*)d_in[21];
    const float* l2_smu = (const float*)d_in[22];
    const float* l2_se  = (const float*)d_in[23];
    const float* l2_w   = (const float*)d_in[25];
    const float* l2_sg  = (const float*)d_in[26];
    const float* l2_mu  = (const float*)d_in[27];
    const float* l2_er  = (const float*)d_in[28];
    const float* l2_gl  = (const float*)d_in[30];
    const float* l2_vl  = (const float*)d_in[31];
    const float* l2_cm  = (const float*)d_in[32];
    const float* l2_ow  = (const float*)d_in[33];
    const float* l2_ob  = (const float*)d_in[34];
    const float* fcw    = (const float*)d_in[35];
    const float* fcb    = (const float*)d_in[36];

    char*  base = (char*)d_ws;
    size_t off  = 0;
    auto alloc = [&](size_t bytes) -> char* {
        char* p = base + off;
        off += (bytes + 255) & ~(size_t)255;
        return p;
    };

    float* h1 = (float*)alloc((size_t)B_SZ * T_STEPS * U1 * 4);
    float* h2 = (float*)alloc((size_t)B_SZ * T_STEPS * 64 * 4);
    // ltc1 interleaved params (8 groups)
    uint4* ABsI1 = (uint4*)alloc((size_t)(S1 / 4) * U1 * 16);
    uint2* WsI1  = (uint2*)alloc((size_t)(S1 / 4) * U1 * 8);
    uint4* ABrI1 = (uint4*)alloc((size_t)(U1 / 4) * U1 * 16);
    uint2* WrI1  = (uint2*)alloc((size_t)(U1 / 4) * U1 * 8);
    // ltc2 interleaved params (4 groups)
    uint4* ABsI2 = (uint4*)alloc((size_t)(S2 / 4) * U2 * 16);
    uint2* WsI2  = (uint2*)alloc((size_t)(S2 / 4) * U2 * 8);
    uint4* ABrI2 = (uint4*)alloc((size_t)(U2 / 4) * U2 * 16);
    uint2* WrI2  = (uint2*)alloc((size_t)(U2 / 4) * U2 * 8);
    // linear fp16 (sens kernels)
    __half2* AB1s = (__half2*)alloc((size_t)S1 * U1 * 4);
    __half*  W1s  = (__half*) alloc((size_t)S1 * U1 * 2);
    __half2* AB2s = (__half2*)alloc((size_t)S2 * U2 * 4);
    __half*  W2s  = (__half*) alloc((size_t)S2 * U2 * 2);
    float* cmt1 = (float*)alloc(U1 * 4);
    float* nb1  = (float*)alloc(U1 * 4);
    float* db1  = (float*)alloc(U1 * 4);
    float* cmt2 = (float*)alloc(U2 * 4);
    float* nb2  = (float*)alloc(U2 * 4);
    float* db2  = (float*)alloc(U2 * 4);

    size_t sens2_bytes = (size_t)B_SZ * T_STEPS * U2 * 4;
    size_t sens1_bytes = (size_t)B_SZ * T_STEPS * U1 * 4;
    bool hoist2 = (off + 2 * sens2_bytes + 512) <= ws_size;
    float* sn2 = nullptr; float* sd2 = nullptr;
    if (hoist2) {
        sn2 = (float*)alloc(sens2_bytes);
        sd2 = (float*)alloc(sens2_bytes);
    }
    bool hoist1 = (off + 2 * sens1_bytes + 512) <= ws_size;
    float* sn1 = nullptr; float* sd1 = nullptr;
    if (hoist1) {
        sn1 = (float*)alloc(sens1_bytes);
        sd1 = (float*)alloc(sens1_bytes);
    }

    // prep
    prep_ilv<<<((S1/4)*U1 + 255)/256, 256, 0, stream>>>(l1_ss, l1_smu, l1_sw, l1_se, ABsI1, WsI1, S1/4, U1, 4, 8);
    prep_ilv<<<((U1/4)*U1 + 255)/256, 256, 0, stream>>>(l1_sg, l1_mu,  l1_w,  l1_er, ABrI1, WrI1, U1/4, U1, 4, 8);
    prep_ilv<<<((S2/4)*U2 + 255)/256, 256, 0, stream>>>(l2_ss, l2_smu, l2_sw, l2_se, ABsI2, WsI2, S2/4, U2, 8, 4);
    prep_ilv<<<((U2/4)*U2 + 255)/256, 256, 0, stream>>>(l2_sg, l2_mu,  l2_w,  l2_er, ABrI2, WrI2, U2/4, U2, 16, 4);
    prep_half<<<(S1 * U1 + 255)/256, 256, 0, stream>>>(l1_ss, l1_smu, l1_sw, l1_se, AB1s, W1s, S1 * U1);
    prep_half<<<(S2 * U2 + 255)/256, 256, 0, stream>>>(l2_ss, l2_smu, l2_sw, l2_se, AB2s, W2s, S2 * U2);
    prep_vec<<<1, 256, 0, stream>>>(l1_gl, l1_vl, l1_cm, cmt1, nb1, db1, U1);
    prep_vec<<<1, 256, 0, stream>>>(l2_gl, l2_vl, l2_cm, cmt2, nb2, db2, U2);

    // layer 1
    if (hoist1) {
        sens1k<<<B_SZ * (T_STEPS / 8), 256, 0, stream>>>(x, l1_iw, l1_ib, AB1s, W1s, sn1, sd1);
        ltc1<true><<<B_SZ, 1024, 0, stream>>>(x, l1_iw, l1_ib, ABsI1, WsI1, ABrI1, WrI1,
                                              sn1, sd1, cmt1, nb1, db1, l1_ow, l1_ob, h1);
    } else {
        ltc1<false><<<B_SZ, 1024, 0, stream>>>(x, l1_iw, l1_ib, ABsI1, WsI1, ABrI1, WrI1,
                                               nullptr, nullptr, cmt1, nb1, db1, l1_ow, l1_ob, h1);
    }

    // layer 2
    if (hoist2) {
        sens2k<<<B_SZ * (T_STEPS / 4), 256, 0, stream>>>(h1, l2_iw, l2_ib, AB2s, W2s, sn2, sd2);
        ltc2<true><<<B_SZ, 1024, 0, stream>>>(h1, l2_iw, l2_ib, ABsI2, WsI2, ABrI2, WrI2,
                                              sn2, sd2, cmt2, nb2, db2, l2_ow, l2_ob, h2);
    } else {
        ltc2<false><<<B_SZ, 1024, 0, stream>>>(h1, l2_iw, l2_ib, ABsI2, WsI2, ABrI2, WrI2,
                                               nullptr, nullptr, cmt2, nb2, db2, l2_ow, l2_ob, h2);
    }
    fc_head<<<B_SZ * T_STEPS / 8, 512, 0, stream>>>(h2, fcw, fcb, (float*)d_out);
}